// Round 2
// baseline (3618.618 us; speedup 1.0000x reference)
//
#include <hip/hip_runtime.h>
#include <stdint.h>

typedef unsigned long long u64;

#define NB   32
#define TST  384
#define IDM  64
#define HDM  128
#define NCLS 10
#define EPSF 1e-7f
#define LOG2E 1.44269504088896340736f

// LDS float offsets
#define O_SBUF 0        // 388 (385 used) cached s_buf
#define O_DELT 388      // 32  deltas from all batches
#define O_MISC 420      // 32: [0..8) s_h partials, [8..16) wsp, [16..24) tb partials
#define O_ACT  452      // 192: x_t(64) | h(128)
#define O_GEX  644      // 256: FC feature [h | attn]
#define O_RED  900      // 1024: per-wave attn partials (8 x 128)
#define O_WFC  1924     // 10*264 = 2640 padded W_fc
#define O_BFC  4564     // 12
#define SMTOT  4576

__device__ __forceinline__ float sigm(float x) {
  return 1.0f / (1.0f + __builtin_amdgcn_exp2f(-LOG2E * x));
}
__device__ __forceinline__ float tanh_f(float x) {
  return 1.0f - 2.0f / (1.0f + __builtin_amdgcn_exp2f(2.0f * LOG2E * x));
}
__device__ __forceinline__ float wave_sum(float v) {
  v += __shfl_xor(v, 1, 64);  v += __shfl_xor(v, 2, 64);
  v += __shfl_xor(v, 4, 64);  v += __shfl_xor(v, 8, 64);
  v += __shfl_xor(v, 16, 64); v += __shfl_xor(v, 32, 64);
  return v;
}

__global__ __attribute__((amdgpu_waves_per_eu(2, 2))) __launch_bounds__(512)
void sab_kernel(const float* __restrict__ x, const float* __restrict__ Wih,
                const float* __restrict__ Whh, const float* __restrict__ bihp,
                const float* __restrict__ bhhp, const float* __restrict__ wtp,
                const float* __restrict__ Wfcp, const float* __restrict__ bfcp,
                float* __restrict__ dout, u64* __restrict__ mail) {
  __shared__ __align__(16) float SM[SMTOT];

  const int tid  = threadIdx.x;
  const int lane = tid & 63;
  const int wv   = tid >> 6;
  const int b    = blockIdx.x;
  const int j    = tid >> 2;          // hidden index 0..127
  const int s    = tid & 3;           // K-slice 0..3 (48 cols each)

  float* hsout = dout + (size_t)NB * TST * NCLS;   // hs region == attention buffer
  const float* myx = x + (size_t)b * TST * IDM;

  // ---- per-thread register weights: 4 gates x 48 K-cols ----
  float w[4][48];
  float bias[4];
  #pragma unroll
  for (int g = 0; g < 4; ++g) {
    const int row = g * HDM + j;
    #pragma unroll
    for (int kk = 0; kk < 48; ++kk) {
      const int k = 48 * s + kk;
      w[g][kk] = (k < IDM) ? Wih[row * IDM + k] : Whh[row * HDM + (k - IDM)];
    }
    bias[g] = bihp[row] + bhhp[row];
  }
  const float wt0 = wtp[j];
  const float wt1 = wtp[HDM + j];

  // top-5 of s_buf (thread 0 only meaningful); s_buf[0]=0 pre-inserted
  float t5a = 0.f, t5b = -3e38f, t5c = -3e38f, t5d = -3e38f, t5e = -3e38f;

  // ---- init LDS ----
  for (int i = tid; i < SMTOT; i += 512) SM[i] = 0.f;
  __syncthreads();
  for (int idx = tid; idx < NCLS * 256; idx += 512)
    SM[O_WFC + (idx >> 8) * 264 + (idx & 255)] = Wfcp[idx];
  if (tid < NCLS) SM[O_BFC + tid] = bfcp[tid];
  if (tid < IDM)  SM[O_ACT + tid] = myx[tid];          // x_0  (h zeroed above)
  if (tid == 0) {
    __hip_atomic_store(&mail[(0 * NB + b) * 8], 0ull, __ATOMIC_RELAXED, __HIP_MEMORY_SCOPE_AGENT);
    __hip_atomic_store(&mail[(1 * NB + b) * 8], 0ull, __ATOMIC_RELAXED, __HIP_MEMORY_SCOPE_AGENT);
  }
  __syncthreads();

  float cst = 0.f, hc = 0.f;

  for (int t = 0; t < TST; ++t) {
    const int r = t + 1;
    const bool big = (r > 5);

    // ---- loop top: t0 finishes s_buf[t] + top-5; FC for step t-1 (off critical path) ----
    if (t > 0) {
      if (tid == 0) {
        float sb = 0.f;
        #pragma unroll
        for (int i = 0; i < 8; ++i) sb += SM[O_MISC + 16 + i];
        SM[O_SBUF + t] = sb;
        if (sb > t5e) {
          if (sb > t5a)      { t5e=t5d; t5d=t5c; t5c=t5b; t5b=t5a; t5a=sb; }
          else if (sb > t5b) { t5e=t5d; t5d=t5c; t5c=t5b; t5b=sb; }
          else if (sb > t5c) { t5e=t5d; t5d=t5c; t5c=sb; }
          else if (sb > t5d) { t5e=t5d; t5d=sb; }
          else               { t5e=sb; }
        }
      }
      if (tid < 160) {
        const int cls = tid >> 4, p = tid & 15;
        float pt = 0.f;
        #pragma unroll
        for (int i = 0; i < 16; ++i) {
          const int k = p + 16 * i;
          pt = fmaf(SM[O_WFC + cls * 264 + k], SM[O_GEX + k], pt);
        }
        pt += __shfl_xor(pt, 1, 64); pt += __shfl_xor(pt, 2, 64);
        pt += __shfl_xor(pt, 4, 64); pt += __shfl_xor(pt, 8, 64);
        if (p == 0) dout[(size_t)(b * TST + (t - 1)) * NCLS + cls] = pt + SM[O_BFC + cls];
      }
    }

    // ================= gates + cell (no LDS exchange, no barrier) =================
    float a0 = 0.f, a1 = 0.f, a2 = 0.f, a3 = 0.f;
    {
      const float4* a4 = reinterpret_cast<const float4*>(SM + O_ACT + 48 * s);
      #pragma unroll
      for (int m = 0; m < 12; ++m) {
        const float4 av = a4[m];
        a0 = fmaf(av.x, w[0][4*m+0], a0); a0 = fmaf(av.y, w[0][4*m+1], a0);
        a0 = fmaf(av.z, w[0][4*m+2], a0); a0 = fmaf(av.w, w[0][4*m+3], a0);
        a1 = fmaf(av.x, w[1][4*m+0], a1); a1 = fmaf(av.y, w[1][4*m+1], a1);
        a1 = fmaf(av.z, w[1][4*m+2], a1); a1 = fmaf(av.w, w[1][4*m+3], a1);
        a2 = fmaf(av.x, w[2][4*m+0], a2); a2 = fmaf(av.y, w[2][4*m+1], a2);
        a2 = fmaf(av.z, w[2][4*m+2], a2); a2 = fmaf(av.w, w[2][4*m+3], a2);
        a3 = fmaf(av.x, w[3][4*m+0], a3); a3 = fmaf(av.y, w[3][4*m+1], a3);
        a3 = fmaf(av.z, w[3][4*m+2], a3); a3 = fmaf(av.w, w[3][4*m+3], a3);
      }
    }
    // butterfly over the 4 K-slices: every lane of the quad gets all 4 full dots
    a0 += __shfl_xor(a0, 1, 64); a0 += __shfl_xor(a0, 2, 64);
    a1 += __shfl_xor(a1, 1, 64); a1 += __shfl_xor(a1, 2, 64);
    a2 += __shfl_xor(a2, 1, 64); a2 += __shfl_xor(a2, 2, 64);
    a3 += __shfl_xor(a3, 1, 64); a3 += __shfl_xor(a3, 2, 64);
    const float iv = sigm(a0 + bias[0]);
    const float fv = sigm(a1 + bias[1]);
    const float gv = tanh_f(a2 + bias[2]);
    const float ov = sigm(a3 + bias[3]);
    cst = fv * cst + iv * gv;
    hc  = ov * tanh_f(cst);

    // s_h partial: one lane per j contributes
    const float shp = wave_sum((s == 0) ? tanh_f(hc) * wt0 : 0.f);
    if (lane == 0) SM[O_MISC + wv] = shp;
    __syncthreads();                                        // B1

    float s_h = 0.f;
    #pragma unroll
    for (int i = 0; i < 8; ++i) s_h += SM[O_MISC + i];

    // ================= delta publish / poll (relaxed, 64B-strided slots) =================
    if (big) {
      if (tid == 0) {
        const u64 pv = (((u64)(unsigned)r) << 32) | (u64)__float_as_uint(t5e + s_h + EPSF);
        __hip_atomic_store(&mail[((r & 1) * NB + b) * 8], pv, __ATOMIC_RELAXED, __HIP_MEMORY_SCOPE_AGENT);
      }
      if (tid < NB) {
        u64* slot = &mail[((r & 1) * NB + tid) * 8];
        u64 v = __hip_atomic_load(slot, __ATOMIC_RELAXED, __HIP_MEMORY_SCOPE_AGENT);
        while ((unsigned)(v >> 32) != (unsigned)r) {
          __builtin_amdgcn_s_sleep(1);
          v = __hip_atomic_load(slot, __ATOMIC_RELAXED, __HIP_MEMORY_SCOPE_AGENT);
        }
        SM[O_DELT + tid] = __uint_as_float((unsigned)v);
      }
    }
    const float sc = s_h + SM[O_SBUF + tid];   // SBUF zero-init => finite for any tid
    __syncthreads();                                        // B2

    // ================= attention weights (per-wave private) =================
    float wval = 0.f; bool pred = false;
    if (big) {
      if (tid < r) {
        wval = fmaxf(sc - SM[O_DELT + ((b * r + tid) & (NB - 1))], 0.f);
        pred = (wval > 0.f) && (tid > 0);
      }
    } else {
      float scv = (tid < r) ? sc : -3e38f;
      float mx = scv;
      mx = fmaxf(mx, __shfl_xor(mx, 1, 64));  mx = fmaxf(mx, __shfl_xor(mx, 2, 64));
      mx = fmaxf(mx, __shfl_xor(mx, 4, 64));  mx = fmaxf(mx, __shfl_xor(mx, 8, 64));
      mx = fmaxf(mx, __shfl_xor(mx, 16, 64)); mx = fmaxf(mx, __shfl_xor(mx, 32, 64));
      if (tid < r) {
        wval = __builtin_amdgcn_exp2f(LOG2E * (scv - mx));
        pred = (tid > 0);
      }
    }
    const u64 m0 = __ballot((int)pred);
    const float wsp = wave_sum(wval);          // includes t'=0 weight (denominator)
    if (lane == 0) SM[O_MISC + 8 + wv] = wsp;

    // gather this wave's own nonzeros (unnormalized); each lane covers 2 of 128 dims
    float g0 = 0.f, g1 = 0.f;
    u64 m = m0;
    while (m) {
      const int l = __builtin_ctzll(m); m &= m - 1;
      const float wgt = __shfl(wval, l, 64);
      const int tp = (wv << 6) + l;
      const float2 v = reinterpret_cast<const float2*>(hsout + (size_t)(b * TST + tp - 1) * HDM)[lane];
      g0 = fmaf(wgt, v.x, g0); g1 = fmaf(wgt, v.y, g1);
    }
    reinterpret_cast<float2*>(SM + O_RED + wv * HDM)[lane] = make_float2(g0, g1);
    __syncthreads();                                        // B4

    // ================= finalize h, stores =================
    float wsum = 0.f;
    #pragma unroll
    for (int i = 0; i < 8; ++i) wsum += SM[O_MISC + 8 + i];
    const float inv = 1.0f / (wsum + (big ? EPSF : 0.0f));
    float attn = 0.f;
    #pragma unroll
    for (int wv2 = 0; wv2 < 8; ++wv2) attn += SM[O_RED + wv2 * HDM + j];
    attn *= inv;
    const float hf = hc + attn;
    if (s == 0) {
      SM[O_ACT + IDM + j] = hf;     // h for next step's gates
      SM[O_GEX + j] = hf;           // FC feature
      SM[O_GEX + HDM + j] = attn;
      hsout[(size_t)(b * TST + t) * HDM + j] = hf;
    }
    if (tid < IDM && t + 1 < TST) SM[O_ACT + tid] = myx[(size_t)(t + 1) * IDM + tid];
    const float tbv = wave_sum((s == 0) ? tanh_f(hf) * wt1 : 0.f);
    if (lane == 0) SM[O_MISC + 16 + wv] = tbv;
    __syncthreads();                                        // B5 (loop top)
  }

  // final FC for t = 383
  if (tid < 160) {
    const int cls = tid >> 4, p = tid & 15;
    float pt = 0.f;
    #pragma unroll
    for (int i = 0; i < 16; ++i) {
      const int k = p + 16 * i;
      pt = fmaf(SM[O_WFC + cls * 264 + k], SM[O_GEX + k], pt);
    }
    pt += __shfl_xor(pt, 1, 64); pt += __shfl_xor(pt, 2, 64);
    pt += __shfl_xor(pt, 4, 64); pt += __shfl_xor(pt, 8, 64);
    if (p == 0) dout[(size_t)(b * TST + (TST - 1)) * NCLS + cls] = pt + SM[O_BFC + cls];
  }
}

extern "C" void kernel_launch(void* const* d_in, const int* in_sizes, int n_in,
                              void* d_out, int out_size, void* d_ws, size_t ws_size,
                              hipStream_t stream) {
  const float* x   = (const float*)d_in[0];
  const float* Wih = (const float*)d_in[1];
  const float* Whh = (const float*)d_in[2];
  const float* bih = (const float*)d_in[3];
  const float* bhh = (const float*)d_in[4];
  const float* wt  = (const float*)d_in[5];
  const float* Wfc = (const float*)d_in[6];
  const float* bfc = (const float*)d_in[7];
  sab_kernel<<<dim3(NB), dim3(512), 0, stream>>>(
      x, Wih, Whh, bih, bhh, wt, Wfc, bfc, (float*)d_out, (u64*)d_ws);
}